// Round 1
// baseline (2909.768 us; speedup 1.0000x reference)
//
#include <hip/hip_runtime.h>
#include <hip/hip_bf16.h>

typedef __bf16 bf16_t;
typedef __bf16 bf16x8 __attribute__((ext_vector_type(8)));
typedef float f32x4 __attribute__((ext_vector_type(4)));

#define HDIM 256
#define TSTEPS 64
#define DIN 64
#define BM 64
#define NBLK 256  // 16384 / 64

__device__ __forceinline__ float fast_tanh(float x) {
    // tanh(x) = 1 - 2/(exp2(2x*log2e)+1); saturates correctly at +-inf
    float e = __builtin_amdgcn_exp2f(x * 2.8853900817779268f);
    return 1.0f - 2.0f * __builtin_amdgcn_rcpf(e + 1.0f);
}
__device__ __forceinline__ float fast_sigmoid(float x) {
    float e = __builtin_amdgcn_exp2f(-x * 1.4426950408889634f);
    return __builtin_amdgcn_rcpf(1.0f + e);
}

// swizzled LDS byte address: row-major [64][256] bf16 (stride 512B),
// kb XOR ((row&7)<<4) spreads the 16-row column reads across banks (G4).
__device__ __forceinline__ unsigned lds_addr(int row, int kb) {
    return (unsigned)(row * 512 + (kb ^ ((row & 7) << 4)));
}

// ---------------- weight packing (prologue) ----------------
// Packed B-fragment layout: elem index ((nt*KC + kc)*64 + lane)*8 + i holds
// W[n = nt*16 + (lane&15)][k = kc*32 + (lane>>4)*8 + i]  (k<ksplit from s0 else s1)
__global__ void pack_w(const float* __restrict__ s0, const float* __restrict__ s1,
                       int ksplit, int stride0, int stride1, int off0, int off1,
                       int KC, bf16_t* __restrict__ dst) {
    int idx = blockIdx.x * 256 + threadIdx.x;
    int total = 256 * KC * 32;
    if (idx >= total) return;
    int i = idx & 7;
    int lane = (idx >> 3) & 63;
    int rest = idx >> 9;  // nt*KC + kc
    int kc = rest % KC, nt = rest / KC;
    int n = nt * 16 + (lane & 15);
    int k = kc * 32 + ((lane >> 4) * 8) + i;
    float v = (k < ksplit) ? s0[n * stride0 + off0 + k]
                           : s1[n * stride1 + off1 + (k - ksplit)];
    dst[idx] = (bf16_t)v;
}

__global__ void pack_bias(const float* __restrict__ b_ih1, const float* __restrict__ b_hh1,
                          const float* __restrict__ b_ih2, const float* __restrict__ b_hh2,
                          const float* __restrict__ b_g,
                          float* __restrict__ bias1, float* __restrict__ bias2a,
                          float* __restrict__ biasg) {
    int j = threadIdx.x;
    bias1[j] = b_ih1[j] + b_hh1[j];
    bias2a[j] = b_ih2[j] + b_hh2[j];
    biasg[j] = b_g[j];
}

// ---------------- main persistent RNN kernel ----------------
__global__ __launch_bounds__(512, 2) void rnn_main(
    const float* __restrict__ x,
    const bf16_t* __restrict__ pw_ih1,   // N=256 K=64  (KC=2)
    const bf16_t* __restrict__ pw_hh1,   // N=256 K=256 (KC=8)
    const bf16_t* __restrict__ pw_2a,    // N=256 K=512 (KC=16): k<256 W_ih2, k>=256 W_hh2
    const bf16_t* __restrict__ pw_2b,    // N=256 K=256 (KC=8): Wg[:, 0:256]
    const bf16_t* __restrict__ pw_3,     // N=256 K=256 (KC=8): Wg[:, 256:512]
    const float* __restrict__ bias1v, const float* __restrict__ bias2av,
    const float* __restrict__ biasgv,
    const float* __restrict__ wo1, const float* __restrict__ bo1p,
    const float* __restrict__ wo2, const float* __restrict__ bo2p,
    float* __restrict__ out) {
    __shared__ char lds[65536];
    char* lh1 = lds;           // [64][256] bf16 swizzled
    char* lh2 = lds + 32768;   // [64][256] bf16 swizzled

    const int tid = threadIdx.x;
    const int wave = tid >> 6, lane = tid & 63;
    const int l15 = lane & 15, l4 = lane >> 4;
    const int b0 = blockIdx.x * BM;

    // zero h1, h2 in LDS (initial state)
    {
        int4 z = {0, 0, 0, 0};
        for (int i = tid; i < 4096; i += 512) ((int4*)lds)[i] = z;
    }

    f32x4 u_reg[4][2], h2_reg[4][2];
#pragma unroll
    for (int mt = 0; mt < 4; ++mt)
#pragma unroll
        for (int n2 = 0; n2 < 2; ++n2) {
            u_reg[mt][n2] = (f32x4){1.f, 1.f, 1.f, 1.f};
            h2_reg[mt][n2] = (f32x4){0.f, 0.f, 0.f, 0.f};
        }

    float bias1_r[2], bias2a_r[2], biasg_r[2];
#pragma unroll
    for (int n2 = 0; n2 < 2; ++n2) {
        int col = wave * 32 + n2 * 16 + l15;
        bias1_r[n2] = bias1v[col];
        bias2a_r[n2] = bias2av[col];
        biasg_r[n2] = biasgv[col];
    }
    const float bo1 = bo1p[0], bo2 = bo2p[0];
    const int orow = tid >> 3, oseg = tid & 7;

    __syncthreads();

    for (int t = 0; t < TSTEPS; ++t) {
        // ================= GEMM1: pre1 = x_t @ W_ih1^T + h1 @ W_hh1^T =================
        f32x4 acc[4][2];
#pragma unroll
        for (int mt = 0; mt < 4; ++mt)
#pragma unroll
            for (int n2 = 0; n2 < 2; ++n2) acc[mt][n2] = (f32x4){0.f, 0.f, 0.f, 0.f};

        // x part (K=64), fp32 global -> bf16 A-frags on the fly
#pragma unroll
        for (int kc = 0; kc < 2; ++kc) {
            bf16x8 bfr[2];
#pragma unroll
            for (int n2 = 0; n2 < 2; ++n2)
                bfr[n2] = *(const bf16x8*)(pw_ih1 + (((wave * 2 + n2) * 2 + kc) * 64 + lane) * 8);
#pragma unroll
            for (int mt = 0; mt < 4; ++mt) {
                const float* xp = x + (size_t)(b0 + mt * 16 + l15) * (TSTEPS * DIN) + t * DIN + kc * 32 + l4 * 8;
                float4 v0 = *(const float4*)xp;
                float4 v1 = *(const float4*)(xp + 4);
                bf16x8 a;
                a[0] = (bf16_t)v0.x; a[1] = (bf16_t)v0.y; a[2] = (bf16_t)v0.z; a[3] = (bf16_t)v0.w;
                a[4] = (bf16_t)v1.x; a[5] = (bf16_t)v1.y; a[6] = (bf16_t)v1.z; a[7] = (bf16_t)v1.w;
#pragma unroll
                for (int n2 = 0; n2 < 2; ++n2)
                    acc[mt][n2] = __builtin_amdgcn_mfma_f32_16x16x32_bf16(a, bfr[n2], acc[mt][n2], 0, 0, 0);
            }
        }
        // h1 part (K=256) from LDS
#pragma unroll
        for (int kc = 0; kc < 8; ++kc) {
            bf16x8 bfr[2], afr[4];
#pragma unroll
            for (int n2 = 0; n2 < 2; ++n2)
                bfr[n2] = *(const bf16x8*)(pw_hh1 + (((wave * 2 + n2) * 8 + kc) * 64 + lane) * 8);
#pragma unroll
            for (int mt = 0; mt < 4; ++mt)
                afr[mt] = *(const bf16x8*)(lh1 + lds_addr(mt * 16 + l15, kc * 64 + l4 * 16));
#pragma unroll
            for (int mt = 0; mt < 4; ++mt)
#pragma unroll
                for (int n2 = 0; n2 < 2; ++n2)
                    acc[mt][n2] = __builtin_amdgcn_mfma_f32_16x16x32_bf16(afr[mt], bfr[n2], acc[mt][n2], 0, 0, 0);
        }
        // h1new = tanh(pre1 + bias1)
        float h1n[4][2][4];
#pragma unroll
        for (int mt = 0; mt < 4; ++mt)
#pragma unroll
            for (int n2 = 0; n2 < 2; ++n2)
#pragma unroll
                for (int r = 0; r < 4; ++r)
                    h1n[mt][n2][r] = fast_tanh(acc[mt][n2][r] + bias1_r[n2]);

        __syncthreads();  // everyone done reading old h1 (and prev out-proj reads)
        // write h1new to LDS (D-frag: row=(l>>4)*4+r, col=l&15)
#pragma unroll
        for (int mt = 0; mt < 4; ++mt)
#pragma unroll
            for (int n2 = 0; n2 < 2; ++n2)
#pragma unroll
                for (int r = 0; r < 4; ++r) {
                    int R = mt * 16 + l4 * 4 + r;
                    int J = wave * 32 + n2 * 16 + l15;
                    *(bf16_t*)(lh1 + lds_addr(R, J * 2)) = (bf16_t)h1n[mt][n2][r];
                }
        __syncthreads();  // h1new visible

        // ============ GEMM2a: z2pre = h1new @ W_ih2^T + h2old @ W_hh2^T (K=512) ============
        // ============ GEMM2b: gpre = h1new @ Wg1^T (K=256) ============
        f32x4 accz[4][2], accg[4][2];
#pragma unroll
        for (int mt = 0; mt < 4; ++mt)
#pragma unroll
            for (int n2 = 0; n2 < 2; ++n2) {
                accz[mt][n2] = (f32x4){0.f, 0.f, 0.f, 0.f};
                accg[mt][n2] = (f32x4){0.f, 0.f, 0.f, 0.f};
            }
#pragma unroll
        for (int kc = 0; kc < 16; ++kc) {
            bf16x8 bfr[2], afr[4];
#pragma unroll
            for (int n2 = 0; n2 < 2; ++n2)
                bfr[n2] = *(const bf16x8*)(pw_2a + (((wave * 2 + n2) * 16 + kc) * 64 + lane) * 8);
            char* src = (kc < 8) ? lh1 : lh2;
            int kcl = kc & 7;
#pragma unroll
            for (int mt = 0; mt < 4; ++mt)
                afr[mt] = *(const bf16x8*)(src + lds_addr(mt * 16 + l15, kcl * 64 + l4 * 16));
#pragma unroll
            for (int mt = 0; mt < 4; ++mt)
#pragma unroll
                for (int n2 = 0; n2 < 2; ++n2)
                    accz[mt][n2] = __builtin_amdgcn_mfma_f32_16x16x32_bf16(afr[mt], bfr[n2], accz[mt][n2], 0, 0, 0);
        }
#pragma unroll
        for (int kc = 0; kc < 8; ++kc) {
            bf16x8 bfr[2], afr[4];
#pragma unroll
            for (int n2 = 0; n2 < 2; ++n2)
                bfr[n2] = *(const bf16x8*)(pw_2b + (((wave * 2 + n2) * 8 + kc) * 64 + lane) * 8);
#pragma unroll
            for (int mt = 0; mt < 4; ++mt)
                afr[mt] = *(const bf16x8*)(lh1 + lds_addr(mt * 16 + l15, kc * 64 + l4 * 16));
#pragma unroll
            for (int mt = 0; mt < 4; ++mt)
#pragma unroll
                for (int n2 = 0; n2 < 2; ++n2)
                    accg[mt][n2] = __builtin_amdgcn_mfma_f32_16x16x32_bf16(afr[mt], bfr[n2], accg[mt][n2], 0, 0, 0);
        }
        // z2 = tanh(...); h2 = u*z2 + (1-u)*h2   (u from previous step; fp32 in regs)
#pragma unroll
        for (int mt = 0; mt < 4; ++mt)
#pragma unroll
            for (int n2 = 0; n2 < 2; ++n2)
#pragma unroll
                for (int r = 0; r < 4; ++r) {
                    float z2 = fast_tanh(accz[mt][n2][r] + bias2a_r[n2]);
                    float u = u_reg[mt][n2][r];
                    h2_reg[mt][n2][r] = u * z2 + (1.f - u) * h2_reg[mt][n2][r];
                }
        __syncthreads();  // everyone done reading old h2
#pragma unroll
        for (int mt = 0; mt < 4; ++mt)
#pragma unroll
            for (int n2 = 0; n2 < 2; ++n2)
#pragma unroll
                for (int r = 0; r < 4; ++r) {
                    int R = mt * 16 + l4 * 4 + r;
                    int J = wave * 32 + n2 * 16 + l15;
                    *(bf16_t*)(lh2 + lds_addr(R, J * 2)) = (bf16_t)h2_reg[mt][n2][r];
                }
        __syncthreads();  // h2new visible

        // ============ GEMM3: gpre += h2new @ Wg2^T (K=256) → u_next ============
#pragma unroll
        for (int kc = 0; kc < 8; ++kc) {
            bf16x8 bfr[2], afr[4];
#pragma unroll
            for (int n2 = 0; n2 < 2; ++n2)
                bfr[n2] = *(const bf16x8*)(pw_3 + (((wave * 2 + n2) * 8 + kc) * 64 + lane) * 8);
#pragma unroll
            for (int mt = 0; mt < 4; ++mt)
                afr[mt] = *(const bf16x8*)(lh2 + lds_addr(mt * 16 + l15, kc * 64 + l4 * 16));
#pragma unroll
            for (int mt = 0; mt < 4; ++mt)
#pragma unroll
                for (int n2 = 0; n2 < 2; ++n2)
                    accg[mt][n2] = __builtin_amdgcn_mfma_f32_16x16x32_bf16(afr[mt], bfr[n2], accg[mt][n2], 0, 0, 0);
        }
#pragma unroll
        for (int mt = 0; mt < 4; ++mt)
#pragma unroll
            for (int n2 = 0; n2 < 2; ++n2)
#pragma unroll
                for (int r = 0; r < 4; ++r)
                    u_reg[mt][n2][r] = fast_sigmoid(accg[mt][n2][r] + biasg_r[n2]);

        // ============ output projection: out = tanh(h1.wo1+b) + tanh(h2.wo2+b) ============
        // 8 threads per row; each sums 32 cols from LDS
        float s1 = 0.f, s2 = 0.f;
#pragma unroll
        for (int c = 0; c < 4; ++c) {
            int kb = oseg * 64 + c * 16;
            bf16x8 hv1 = *(const bf16x8*)(lh1 + lds_addr(orow, kb));
            bf16x8 hv2 = *(const bf16x8*)(lh2 + lds_addr(orow, kb));
            const float* w1p = wo1 + oseg * 32 + c * 8;
            const float* w2p = wo2 + oseg * 32 + c * 8;
            float4 w10 = *(const float4*)w1p, w11 = *(const float4*)(w1p + 4);
            float4 w20 = *(const float4*)w2p, w21 = *(const float4*)(w2p + 4);
            s1 += (float)hv1[0] * w10.x + (float)hv1[1] * w10.y + (float)hv1[2] * w10.z + (float)hv1[3] * w10.w;
            s1 += (float)hv1[4] * w11.x + (float)hv1[5] * w11.y + (float)hv1[6] * w11.z + (float)hv1[7] * w11.w;
            s2 += (float)hv2[0] * w20.x + (float)hv2[1] * w20.y + (float)hv2[2] * w20.z + (float)hv2[3] * w20.w;
            s2 += (float)hv2[4] * w21.x + (float)hv2[5] * w21.y + (float)hv2[6] * w21.z + (float)hv2[7] * w21.w;
        }
        s1 += __shfl_xor(s1, 1, 8); s1 += __shfl_xor(s1, 2, 8); s1 += __shfl_xor(s1, 4, 8);
        s2 += __shfl_xor(s2, 1, 8); s2 += __shfl_xor(s2, 2, 8); s2 += __shfl_xor(s2, 4, 8);
        if (oseg == 0)
            out[(size_t)(b0 + orow) * TSTEPS + t] = fast_tanh(s1 + bo1) + fast_tanh(s2 + bo2);
        // loop back: GEMM1 of t+1 reads lh1 (stable until next "write h1" barrier)
    }
}

extern "C" void kernel_launch(void* const* d_in, const int* in_sizes, int n_in,
                              void* d_out, int out_size, void* d_ws, size_t ws_size,
                              hipStream_t stream) {
    const float* x = (const float*)d_in[0];
    const float* W_ih1 = (const float*)d_in[1];
    const float* b_ih1 = (const float*)d_in[2];
    const float* W_hh1 = (const float*)d_in[3];
    const float* b_hh1 = (const float*)d_in[4];
    const float* W_ih2 = (const float*)d_in[5];
    const float* b_ih2 = (const float*)d_in[6];
    const float* W_hh2 = (const float*)d_in[7];
    const float* b_hh2 = (const float*)d_in[8];
    const float* W_o1 = (const float*)d_in[9];
    const float* b_o1 = (const float*)d_in[10];
    const float* W_o2 = (const float*)d_in[11];
    const float* b_o2 = (const float*)d_in[12];
    const float* W_g = (const float*)d_in[13];
    const float* b_g = (const float*)d_in[14];

    char* ws = (char*)d_ws;
    bf16_t* pw_ih1 = (bf16_t*)(ws + 0);        // 32768 B
    bf16_t* pw_hh1 = (bf16_t*)(ws + 32768);    // 131072 B
    bf16_t* pw_2a = (bf16_t*)(ws + 163840);    // 262144 B
    bf16_t* pw_2b = (bf16_t*)(ws + 425984);    // 131072 B
    bf16_t* pw_3 = (bf16_t*)(ws + 557056);     // 131072 B
    float* bias1 = (float*)(ws + 688128);
    float* bias2a = (float*)(ws + 689152);
    float* biasg = (float*)(ws + 690176);

    // prologue: pack weights into B-fragment-linear bf16 layouts
    pack_w<<<32 * 2, 256, 0, stream>>>(W_ih1, W_ih1, 64, 64, 64, 0, 0, 2, pw_ih1);
    pack_w<<<32 * 8, 256, 0, stream>>>(W_hh1, W_hh1, 256, 256, 256, 0, 0, 8, pw_hh1);
    pack_w<<<32 * 16, 256, 0, stream>>>(W_ih2, W_hh2, 256, 256, 256, 0, 0, 16, pw_2a);
    pack_w<<<32 * 8, 256, 0, stream>>>(W_g, W_g, 256, 512, 512, 0, 0, 8, pw_2b);
    pack_w<<<32 * 8, 256, 0, stream>>>(W_g, W_g, 256, 512, 512, 256, 0, 8, pw_3);
    pack_bias<<<1, 256, 0, stream>>>(b_ih1, b_hh1, b_ih2, b_hh2, b_g, bias1, bias2a, biasg);

    rnn_main<<<NBLK, 512, 0, stream>>>(x, pw_ih1, pw_hh1, pw_2a, pw_2b, pw_3,
                                       bias1, bias2a, biasg, W_o1, b_o1, W_o2, b_o2,
                                       (float*)d_out);
}

// Round 3
// 1918.237 us; speedup vs baseline: 1.5169x; 1.5169x over previous
//
#include <hip/hip_runtime.h>
#include <hip/hip_bf16.h>

typedef __bf16 bf16_t;
typedef __bf16 bf16x8 __attribute__((ext_vector_type(8)));
typedef float f32x4 __attribute__((ext_vector_type(4)));

#define HDIM 256
#define TSTEPS 64
#define DIN 64
#define BM 64
#define NBLK 256  // 16384 / 64

__device__ __forceinline__ float fast_tanh(float x) {
    float e = __builtin_amdgcn_exp2f(x * 2.8853900817779268f);
    return 1.0f - 2.0f * __builtin_amdgcn_rcpf(e + 1.0f);
}
__device__ __forceinline__ float fast_sigmoid(float x) {
    float e = __builtin_amdgcn_exp2f(-x * 1.4426950408889634f);
    return __builtin_amdgcn_rcpf(1.0f + e);
}

// swizzled LDS byte address: row-major [64][256] bf16 (stride 512B)
__device__ __forceinline__ unsigned lds_addr(int row, int kb) {
    return (unsigned)(row * 512 + (kb ^ ((row & 7) << 4)));
}

// ---------------- weight packing (prologue) ----------------
// Chunk layout (kc-major, n2-minor for phase pairing):
//   chunk = (wave*KC + kc)*2 + n2, element ((chunk)*64 + lane)*8 + i holds
//   W[n = (wave*2+n2)*16 + (lane&15)][k = kc*32 + (lane>>4)*8 + i]
__global__ void pack_w(const float* __restrict__ s0, const float* __restrict__ s1,
                       int ksplit, int stride0, int stride1, int off0, int off1,
                       int KC, bf16_t* __restrict__ dst) {
    int idx = blockIdx.x * 256 + threadIdx.x;
    int total = 256 * KC * 32;
    if (idx >= total) return;
    int i = idx & 7;
    int lane = (idx >> 3) & 63;
    int chunk = idx >> 9;
    int n2 = chunk & 1;
    int rest = chunk >> 1;
    int kc = rest % KC, wv = rest / KC;
    int nt = wv * 2 + n2;
    int n = nt * 16 + (lane & 15);
    int k = kc * 32 + ((lane >> 4) * 8) + i;
    float v = (k < ksplit) ? s0[n * stride0 + off0 + k]
                           : s1[n * stride1 + off1 + (k - ksplit)];
    dst[idx] = (bf16_t)v;
}

__global__ void pack_bias(const float* __restrict__ b_ih1, const float* __restrict__ b_hh1,
                          const float* __restrict__ b_ih2, const float* __restrict__ b_hh2,
                          const float* __restrict__ b_g,
                          float* __restrict__ bias1, float* __restrict__ bias2a,
                          float* __restrict__ biasg) {
    int j = threadIdx.x;
    bias1[j] = b_ih1[j] + b_hh1[j];
    bias2a[j] = b_ih2[j] + b_hh2[j];
    biasg[j] = b_g[j];
}

#define ISSUE(BUF, PB, N)                                            \
    _Pragma("unroll") for (int c = 0; c < (N); ++c)                  \
        BUF[c] = *(const bf16x8*)((PB) + c * 512 + (lane << 3));

#define GEMM_PH(NKK, BUF, ASRC, KC0, ACC)                                             \
    _Pragma("unroll") for (int kk = 0; kk < (NKK); ++kk) {                            \
        bf16x8 a_[4];                                                                 \
        _Pragma("unroll") for (int mt = 0; mt < 4; ++mt)                              \
            a_[mt] = *(const bf16x8*)((ASRC) + lds_addr(mt * 16 + l15,                \
                                                        ((KC0) + kk) * 64 + l4 * 16));\
        _Pragma("unroll") for (int mt = 0; mt < 4; ++mt) {                            \
            ACC[mt][0] = __builtin_amdgcn_mfma_f32_16x16x32_bf16(a_[mt], BUF[kk * 2 + 0], ACC[mt][0], 0, 0, 0); \
            ACC[mt][1] = __builtin_amdgcn_mfma_f32_16x16x32_bf16(a_[mt], BUF[kk * 2 + 1], ACC[mt][1], 0, 0, 0); \
        }                                                                             \
    }

// ---------------- main persistent RNN kernel ----------------
__global__ __launch_bounds__(512, 2) void rnn_main(
    const float* __restrict__ x,
    const bf16_t* __restrict__ pw_ih1,   // N=256 K=64  (KC=2)
    const bf16_t* __restrict__ pw_hh1,   // N=256 K=256 (KC=8)
    const bf16_t* __restrict__ pw_2a,    // N=256 K=512 (KC=16): k<256 W_ih2, k>=256 W_hh2
    const bf16_t* __restrict__ pw_2b,    // N=256 K=256 (KC=8): Wg[:, 0:256]
    const bf16_t* __restrict__ pw_3,     // N=256 K=256 (KC=8): Wg[:, 256:512]
    const float* __restrict__ bias1v, const float* __restrict__ bias2av,
    const float* __restrict__ biasgv,
    const float* __restrict__ wo1, const float* __restrict__ bo1p,
    const float* __restrict__ wo2, const float* __restrict__ bo2p,
    float* __restrict__ out) {
    __shared__ char lds[65536];
    char* lh1 = lds;           // [64][256] bf16 swizzled
    char* lh2 = lds + 32768;   // [64][256] bf16 swizzled

    const int tid = threadIdx.x;
    const int wave = tid >> 6, lane = tid & 63;
    const int l15 = lane & 15, l4 = lane >> 4;
    const int b0 = blockIdx.x * BM;

    {   // zero h1, h2 in LDS (initial state)
        int4 z = {0, 0, 0, 0};
        for (int i = tid; i < 4096; i += 512) ((int4*)lds)[i] = z;
    }

    f32x4 u_reg[4][2];
#pragma unroll
    for (int mt = 0; mt < 4; ++mt)
#pragma unroll
        for (int n2 = 0; n2 < 2; ++n2) u_reg[mt][n2] = (f32x4){1.f, 1.f, 1.f, 1.f};

    float bias1_r[2], bias2a_r[2], biasg_r[2];
#pragma unroll
    for (int n2 = 0; n2 < 2; ++n2) {
        int col = wave * 32 + n2 * 16 + l15;
        bias1_r[n2] = bias1v[col];
        bias2a_r[n2] = bias2av[col];
        biasg_r[n2] = biasgv[col];
    }
    const float bo1 = bo1p[0], bo2 = bo2p[0];
    const int orow = tid >> 3, oseg = tid & 7;

    // per-wave contiguous stream bases (element offsets)
    const bf16_t* base_ih1 = pw_ih1 + wave * 2048;    // 4 chunks
    const bf16_t* base_hh1 = pw_hh1 + wave * 8192;    // 16 chunks
    const bf16_t* base_2a  = pw_2a  + wave * 16384;   // 32 chunks
    const bf16_t* base_2b  = pw_2b  + wave * 8192;    // 16 chunks
    const bf16_t* base_3   = pw_3   + wave * 8192;    // 16 chunks

    bf16x8 bufA[8], bufB[8];
    bf16x8 xpre[8];  // [kc*4+mt]

    // prologue: prefetch ih1 into A; x(t=0) into xpre
    ISSUE(bufA, base_ih1, 4);
    {
#pragma unroll
        for (int kc = 0; kc < 2; ++kc)
#pragma unroll
            for (int mt = 0; mt < 4; ++mt) {
                const float* xp = x + (size_t)(b0 + mt * 16 + l15) * (TSTEPS * DIN) + kc * 32 + l4 * 8;
                f32x4 v0 = __builtin_nontemporal_load((const f32x4*)xp);
                f32x4 v1 = __builtin_nontemporal_load((const f32x4*)(xp + 4));
                bf16x8 a;
                a[0] = (bf16_t)v0[0]; a[1] = (bf16_t)v0[1]; a[2] = (bf16_t)v0[2]; a[3] = (bf16_t)v0[3];
                a[4] = (bf16_t)v1[0]; a[5] = (bf16_t)v1[1]; a[6] = (bf16_t)v1[2]; a[7] = (bf16_t)v1[3];
                xpre[kc * 4 + mt] = a;
            }
    }

    __syncthreads();

    for (int t = 0; t < TSTEPS; ++t) {
        // ---- P0: consume A=ih1 (x-GEMM) | load B <- hh1[kc0-3] ----
        f32x4 acc[4][2];
#pragma unroll
        for (int mt = 0; mt < 4; ++mt)
#pragma unroll
            for (int n2 = 0; n2 < 2; ++n2) acc[mt][n2] = (f32x4){0.f, 0.f, 0.f, 0.f};
        ISSUE(bufB, base_hh1, 8);
#pragma unroll
        for (int kk = 0; kk < 2; ++kk)
#pragma unroll
            for (int mt = 0; mt < 4; ++mt) {
                acc[mt][0] = __builtin_amdgcn_mfma_f32_16x16x32_bf16(xpre[kk * 4 + mt], bufA[kk * 2 + 0], acc[mt][0], 0, 0, 0);
                acc[mt][1] = __builtin_amdgcn_mfma_f32_16x16x32_bf16(xpre[kk * 4 + mt], bufA[kk * 2 + 1], acc[mt][1], 0, 0, 0);
            }
        // ---- P1: consume B=hh1 kc0-3 (A from lh1) | load A <- hh1[kc4-7] ----
        ISSUE(bufA, base_hh1 + 4096, 8);
        GEMM_PH(4, bufB, lh1, 0, acc)
        // ---- P2: consume A=hh1 kc4-7 | load B <- 2a[kc0-3] ----
        ISSUE(bufB, base_2a, 8);
        GEMM_PH(4, bufA, lh1, 4, acc)

        // ---- h1 epilogue ----
        float h1n[4][2][4];
#pragma unroll
        for (int mt = 0; mt < 4; ++mt)
#pragma unroll
            for (int n2 = 0; n2 < 2; ++n2)
#pragma unroll
                for (int r = 0; r < 4; ++r)
                    h1n[mt][n2][r] = fast_tanh(acc[mt][n2][r] + bias1_r[n2]);
        __syncthreads();  // all waves done reading old lh1 (and prev out-proj)
#pragma unroll
        for (int mt = 0; mt < 4; ++mt)
#pragma unroll
            for (int n2 = 0; n2 < 2; ++n2)
#pragma unroll
                for (int r = 0; r < 4; ++r)
                    *(bf16_t*)(lh1 + lds_addr(mt * 16 + l4 * 4 + r,
                                              (wave * 32 + n2 * 16 + l15) * 2)) = (bf16_t)h1n[mt][n2][r];
        __syncthreads();  // h1new visible

        // ---- P3..P6: GEMM2a (z2pre), K=512: kc0-7 from lh1(new), kc8-15 from lh2(old) ----
        f32x4 accz[4][2];
#pragma unroll
        for (int mt = 0; mt < 4; ++mt)
#pragma unroll
            for (int n2 = 0; n2 < 2; ++n2) accz[mt][n2] = (f32x4){0.f, 0.f, 0.f, 0.f};
        ISSUE(bufA, base_2a + 4096, 8);
        GEMM_PH(4, bufB, lh1, 0, accz)          // P3: 2a kc0-3
        ISSUE(bufB, base_2a + 8192, 8);
        GEMM_PH(4, bufA, lh1, 4, accz)          // P4: 2a kc4-7
        ISSUE(bufA, base_2a + 12288, 8);
        GEMM_PH(4, bufB, lh2, 0, accz)          // P5: 2a kc8-11 (h2 old)
        ISSUE(bufB, base_2b, 8);
        GEMM_PH(4, bufA, lh2, 4, accz)          // P6: 2a kc12-15 (h2 old)

        // ---- blend: z2 = tanh(accz+b); h2 = u*z2 + (1-u)*h2old (h2old from LDS bf16) ----
        float h2n[4][2][4];
#pragma unroll
        for (int mt = 0; mt < 4; ++mt)
#pragma unroll
            for (int n2 = 0; n2 < 2; ++n2)
#pragma unroll
                for (int r = 0; r < 4; ++r) {
                    float z2 = fast_tanh(accz[mt][n2][r] + bias2a_r[n2]);
                    float h2o = (float)*(const bf16_t*)(lh2 + lds_addr(mt * 16 + l4 * 4 + r,
                                                                       (wave * 32 + n2 * 16 + l15) * 2));
                    float un = u_reg[mt][n2][r];
                    h2n[mt][n2][r] = un * z2 + (1.f - un) * h2o;
                }
        __syncthreads();  // all waves done reading old lh2
#pragma unroll
        for (int mt = 0; mt < 4; ++mt)
#pragma unroll
            for (int n2 = 0; n2 < 2; ++n2)
#pragma unroll
                for (int r = 0; r < 4; ++r)
                    *(bf16_t*)(lh2 + lds_addr(mt * 16 + l4 * 4 + r,
                                              (wave * 32 + n2 * 16 + l15) * 2)) = (bf16_t)h2n[mt][n2][r];

        // ---- P7 (inside h2-write barrier window, touches lh1 only): 2b kc0-3 ----
        f32x4 accg[4][2];
#pragma unroll
        for (int mt = 0; mt < 4; ++mt)
#pragma unroll
            for (int n2 = 0; n2 < 2; ++n2) accg[mt][n2] = (f32x4){0.f, 0.f, 0.f, 0.f};
        ISSUE(bufA, base_2b + 4096, 8);
        GEMM_PH(4, bufB, lh1, 0, accg)
        __syncthreads();  // h2new visible

        // ---- P8: 2b kc4-7 | load B <- w3[kc0-3]; also issue x(t+1) ----
        ISSUE(bufB, base_3, 8);
        f32x4 xf[4][2][2];
        {
            int tn = t + 1; if (tn > TSTEPS - 1) tn = TSTEPS - 1;
#pragma unroll
            for (int kc = 0; kc < 2; ++kc)
#pragma unroll
                for (int mt = 0; mt < 4; ++mt) {
                    const float* xp = x + (size_t)(b0 + mt * 16 + l15) * (TSTEPS * DIN) + tn * DIN + kc * 32 + l4 * 8;
                    xf[mt][kc][0] = __builtin_nontemporal_load((const f32x4*)xp);
                    xf[mt][kc][1] = __builtin_nontemporal_load((const f32x4*)(xp + 4));
                }
        }
        GEMM_PH(4, bufA, lh1, 4, accg)
        // ---- P9: w3 kc0-3 (h2 new) | load A <- w3[kc4-5] ----
        ISSUE(bufA, base_3 + 4096, 4);
        GEMM_PH(4, bufB, lh2, 0, accg)
        // ---- P10: w3 kc4-5 | load B <- w3[kc6-7] ----
        ISSUE(bufB, base_3 + 6144, 4);
        GEMM_PH(2, bufA, lh2, 4, accg)
        // ---- P11: w3 kc6-7 | load A <- ih1 (ring wraps to next t) ----
        ISSUE(bufA, base_ih1, 4);
        GEMM_PH(2, bufB, lh2, 6, accg)

        // ---- u = sigmoid(gpre + b_g) ----
#pragma unroll
        for (int mt = 0; mt < 4; ++mt)
#pragma unroll
            for (int n2 = 0; n2 < 2; ++n2)
#pragma unroll
                for (int r = 0; r < 4; ++r)
                    u_reg[mt][n2][r] = fast_sigmoid(accg[mt][n2][r] + biasg_r[n2]);

        // ---- output projection: out = tanh(h1.wo1+b) + tanh(h2.wo2+b) ----
        float s1 = 0.f, s2 = 0.f;
#pragma unroll
        for (int c = 0; c < 4; ++c) {
            int kb = oseg * 64 + c * 16;
            bf16x8 hv1 = *(const bf16x8*)(lh1 + lds_addr(orow, kb));
            bf16x8 hv2 = *(const bf16x8*)(lh2 + lds_addr(orow, kb));
            const float* w1p = wo1 + oseg * 32 + c * 8;
            const float* w2p = wo2 + oseg * 32 + c * 8;
            float4 w10 = *(const float4*)w1p, w11 = *(const float4*)(w1p + 4);
            float4 w20 = *(const float4*)w2p, w21 = *(const float4*)(w2p + 4);
            s1 += (float)hv1[0] * w10.x + (float)hv1[1] * w10.y + (float)hv1[2] * w10.z + (float)hv1[3] * w10.w;
            s1 += (float)hv1[4] * w11.x + (float)hv1[5] * w11.y + (float)hv1[6] * w11.z + (float)hv1[7] * w11.w;
            s2 += (float)hv2[0] * w20.x + (float)hv2[1] * w20.y + (float)hv2[2] * w20.z + (float)hv2[3] * w20.w;
            s2 += (float)hv2[4] * w21.x + (float)hv2[5] * w21.y + (float)hv2[6] * w21.z + (float)hv2[7] * w21.w;
        }
        s1 += __shfl_xor(s1, 1, 8); s1 += __shfl_xor(s1, 2, 8); s1 += __shfl_xor(s1, 4, 8);
        s2 += __shfl_xor(s2, 1, 8); s2 += __shfl_xor(s2, 2, 8); s2 += __shfl_xor(s2, 4, 8);
        if (oseg == 0)
            out[(size_t)(b0 + orow) * TSTEPS + t] = fast_tanh(s1 + bo1) + fast_tanh(s2 + bo2);

        // ---- convert x(t+1) to bf16 A-frags (late, so loads overlapped P8..P11) ----
#pragma unroll
        for (int kc = 0; kc < 2; ++kc)
#pragma unroll
            for (int mt = 0; mt < 4; ++mt) {
                f32x4 v0 = xf[mt][kc][0], v1 = xf[mt][kc][1];
                bf16x8 a;
                a[0] = (bf16_t)v0[0]; a[1] = (bf16_t)v0[1]; a[2] = (bf16_t)v0[2]; a[3] = (bf16_t)v0[3];
                a[4] = (bf16_t)v1[0]; a[5] = (bf16_t)v1[1]; a[6] = (bf16_t)v1[2]; a[7] = (bf16_t)v1[3];
                xpre[kc * 4 + mt] = a;
            }
    }
}

extern "C" void kernel_launch(void* const* d_in, const int* in_sizes, int n_in,
                              void* d_out, int out_size, void* d_ws, size_t ws_size,
                              hipStream_t stream) {
    const float* x = (const float*)d_in[0];
    const float* W_ih1 = (const float*)d_in[1];
    const float* b_ih1 = (const float*)d_in[2];
    const float* W_hh1 = (const float*)d_in[3];
    const float* b_hh1 = (const float*)d_in[4];
    const float* W_ih2 = (const float*)d_in[5];
    const float* b_ih2 = (const float*)d_in[6];
    const float* W_hh2 = (const float*)d_in[7];
    const float* b_hh2 = (const float*)d_in[8];
    const float* W_o1 = (const float*)d_in[9];
    const float* b_o1 = (const float*)d_in[10];
    const float* W_o2 = (const float*)d_in[11];
    const float* b_o2 = (const float*)d_in[12];
    const float* W_g = (const float*)d_in[13];
    const float* b_g = (const float*)d_in[14];

    char* ws = (char*)d_ws;
    bf16_t* pw_ih1 = (bf16_t*)(ws + 0);        // 32768 B
    bf16_t* pw_hh1 = (bf16_t*)(ws + 32768);    // 131072 B
    bf16_t* pw_2a = (bf16_t*)(ws + 163840);    // 262144 B
    bf16_t* pw_2b = (bf16_t*)(ws + 425984);    // 131072 B
    bf16_t* pw_3 = (bf16_t*)(ws + 557056);     // 131072 B
    float* bias1 = (float*)(ws + 688128);
    float* bias2a = (float*)(ws + 689152);
    float* biasg = (float*)(ws + 690176);

    pack_w<<<32 * 2, 256, 0, stream>>>(W_ih1, W_ih1, 64, 64, 64, 0, 0, 2, pw_ih1);
    pack_w<<<32 * 8, 256, 0, stream>>>(W_hh1, W_hh1, 256, 256, 256, 0, 0, 8, pw_hh1);
    pack_w<<<32 * 16, 256, 0, stream>>>(W_ih2, W_hh2, 256, 256, 256, 0, 0, 16, pw_2a);
    pack_w<<<32 * 8, 256, 0, stream>>>(W_g, W_g, 256, 512, 512, 0, 0, 8, pw_2b);
    pack_w<<<32 * 8, 256, 0, stream>>>(W_g, W_g, 256, 512, 512, 256, 0, 8, pw_3);
    pack_bias<<<1, 256, 0, stream>>>(b_ih1, b_hh1, b_ih2, b_hh2, b_g, bias1, bias2a, biasg);

    rnn_main<<<NBLK, 512, 0, stream>>>(x, pw_ih1, pw_hh1, pw_2a, pw_2b, pw_3,
                                       bias1, bias2a, biasg, W_o1, b_o1, W_o2, b_o2,
                                       (float*)d_out);
}